// Round 18
// baseline (105.347 us; speedup 1.0000x reference)
//
#include <hip/hip_runtime.h>
#include <hip/hip_bf16.h>

#define NEDGE 320000
#define NNODE 20000
#define MP    20096      // 628*32 padded rows
#define NRELS 8
#define FEAT  128
#define HID   256
#define EMB   128
#define NGRAPH 20
#define NPG   1000
#define NBASE 4
#define PAD   96         // max degree slack (Poisson(16), P(deg>=96) ~ 1e-40)

typedef __attribute__((ext_vector_type(4))) float f32x4;
typedef __attribute__((ext_vector_type(8))) __bf16 bf16x8;
typedef __attribute__((ext_vector_type(8))) unsigned short u16x8;

static __device__ __forceinline__ float bf2f(unsigned short u){
  union { unsigned int i; float f; } v; v.i = ((unsigned int)u) << 16; return v.f;
}
static __device__ __forceinline__ unsigned short f2bf(float f){
  union { float f; unsigned int i; } v; v.f = f;
  unsigned int x = v.i;
  return (unsigned short)((x + 0x7fffu + ((x >> 16) & 1u)) >> 16);
}

__device__ __forceinline__ void load_lds16(const void* g, void* l){
  __builtin_amdgcn_global_load_lds((const __attribute__((address_space(1))) void*)g,
                                   (__attribute__((address_space(3))) void*)l, 16, 0, 0);
}

// ---------------- init: zero per-node cursor + me ----------------
__global__ void k_zeroMe(int* __restrict__ cursor,
                         const float* __restrict__ x, const float* __restrict__ mw,
                         const float* __restrict__ mb, float* __restrict__ me){
  int blk = blockIdx.x;
  if (blk < 79){
    int i = blk*256 + threadIdx.x;
    if (i < NNODE) cursor[i] = 0;
  } else {
    int id = (blk-79)*256 + threadIdx.x;
    if (id >= NGRAPH*EMB) return;
    int g = id >> 7, e = id & 127;
    float s = mb[e];
    for (int i=0;i<HID;i++) s += x[g*HID + i] * mw[i*EMB + e];
    me[id] = s;
  }
}

// ---------------- fused direct-slot scatter + weight prep ----------------
// blocks [0,1250): scatter ; [1250,3750): xb cvt (float4) ; [3750,4390): B1t ; [4390,10790): v
__global__ void k_prepScatter(const int* __restrict__ ei, const int* __restrict__ et,
                              int* __restrict__ cursor, unsigned int* __restrict__ spk,
                              const float* __restrict__ xin, unsigned short* __restrict__ xb,
                              const float* __restrict__ basis, const float* __restrict__ root,
                              unsigned short* __restrict__ Bt,
                              const float* __restrict__ basis2, const float* __restrict__ root2,
                              const float* __restrict__ me, float* __restrict__ v){
  int blk = blockIdx.x;
  if (blk < 1250){
    int e = blk*256 + threadIdx.x;
    if (e < NEDGE){
      int src = ei[e];
      int r = et[e];
      int dst = ei[NEDGE + e];
      int pos = atomicAdd(&cursor[dst], 1);
      if (pos < PAD) spk[(size_t)dst*PAD + pos] = (unsigned int)src | ((unsigned int)r << 15);
    }
  } else if (blk < 3750){
    int i = (blk-1250)*1024 + threadIdx.x*4;
    if (i < NNODE*FEAT){
      float4 f = *(const float4*)(xin + i);
      ushort4 o;
      o.x = f2bf(f.x); o.y = f2bf(f.y); o.z = f2bf(f.z); o.w = f2bf(f.w);
      *(ushort4*)(xb + i) = o;
    }
  } else if (blk < 4390){
    int idx = (blk-3750)*256 + threadIdx.x;
    if (idx >= 256*640) return;
    int o = idx / 640, k = idx % 640;
    float val = (k < 512) ? basis[(size_t)k*256 + o] : root[(size_t)(k-512)*256 + o];
    Bt[(size_t)o*640 + k] = f2bf(val);
  } else {
    int w = threadIdx.x >> 6, lane = threadIdx.x & 63;
    int id = (blk-4390)*4 + w;
    if (id >= NGRAPH*1280) return;
    int g = id / 1280, k = id % 1280;
    const float* row = (k < 1024) ? (basis2 + (size_t)k*EMB) : (root2 + (size_t)(k-1024)*EMB);
    float2 a = *(const float2*)(row + lane*2);
    float2 m = *(const float2*)(me + g*EMB + lane*2);
    float p = a.x*m.x + a.y*m.y;
    #pragma unroll
    for (int d=32; d; d>>=1) p += __shfl_down(p, d);
    if (lane == 0) v[(size_t)g*1280 + k] = p;
  }
}

// ---------------- layer1 aggregation (16-lane groups, 16-deep load batch) + packV ----------------
__global__ void k_agg1(const unsigned short* __restrict__ xb, const int* __restrict__ cursor,
                       const unsigned int* __restrict__ spk,
                       const float* __restrict__ comp1, unsigned short* __restrict__ s1,
                       const float* __restrict__ v, unsigned short* __restrict__ BtV){
  if (blockIdx.x >= 1250){
    int idx = (blockIdx.x-1250)*256 + threadIdx.x;
    if (idx >= 128*256) return;
    int c = idx >> 8, k = idx & 255;
    float val = 0.f;
    if (c < 80)        val = v[(size_t)(c>>2)*1280 + (c&3)*256 + k];
    else if (c < 100)  val = v[(size_t)(c-80)*1280 + 1024 + k];
    BtV[idx] = f2bf(val);
    return;
  }
  __shared__ float c1s[32];
  __shared__ float wcomb[16*32];   // per-group combined weights comp1[r][b]/cnt_r
  if (threadIdx.x < 32) c1s[threadIdx.x] = comp1[threadIdx.x];
  __syncthreads();
  int grp = threadIdx.x >> 4, sl = threadIdx.x & 15;
  int n = blockIdx.x*16 + grp;
  int C = cursor[n]; if (C > PAD) C = PAD;
  const unsigned int* pp = spk + (size_t)n*PAD;
  // pre-pass: lanes 0..7 count their rel, write combined weights (wave-coherent LDS)
  if (sl < 8){
    int c = 0;
    for (int j=0;j<C;j++) c += (int)(((pp[j] >> 15) & 7) == (unsigned)sl);
    float inv = (c > 0) ? __builtin_amdgcn_rcpf((float)c) : 0.f;
    #pragma unroll
    for (int b=0;b<NBASE;b++) wcomb[grp*32 + sl*4 + b] = c1s[sl*4+b]*inv;
  }
  const float* wg = wcomb + grp*32;
  float u[NBASE][8] = {};
  int j = 0;
  // 16-deep: all 16 gathers in flight before any compute
  for (; j+16 <= C; j += 16){
    unsigned int pk[16];
    u16x8 vv[16];
    #pragma unroll
    for (int t=0;t<16;t++) pk[t] = pp[j+t];
    #pragma unroll
    for (int t=0;t<16;t++) vv[t] = *(const u16x8*)(xb + (size_t)(pk[t] & 0x7FFF)*FEAT + sl*8);
    #pragma unroll
    for (int t=0;t<16;t++){
      const float* cr = wg + ((pk[t] >> 15) & 7)*4;
      #pragma unroll
      for (int b=0;b<NBASE;b++){
        float wb = cr[b];
        #pragma unroll
        for (int k=0;k<8;k++) u[b][k] += wb*bf2f(vv[t][k]);
      }
    }
  }
  for (; j+8 <= C; j += 8){
    unsigned int pk[8];
    u16x8 vv[8];
    #pragma unroll
    for (int t=0;t<8;t++) pk[t] = pp[j+t];
    #pragma unroll
    for (int t=0;t<8;t++) vv[t] = *(const u16x8*)(xb + (size_t)(pk[t] & 0x7FFF)*FEAT + sl*8);
    #pragma unroll
    for (int t=0;t<8;t++){
      const float* cr = wg + ((pk[t] >> 15) & 7)*4;
      #pragma unroll
      for (int b=0;b<NBASE;b++){
        float wb = cr[b];
        #pragma unroll
        for (int k=0;k<8;k++) u[b][k] += wb*bf2f(vv[t][k]);
      }
    }
  }
  for (; j < C; ++j){
    unsigned int pk = pp[j];
    u16x8 vv = *(const u16x8*)(xb + (size_t)(pk & 0x7FFF)*FEAT + sl*8);
    const float* cr = wg + ((pk >> 15) & 7)*4;
    #pragma unroll
    for (int b=0;b<NBASE;b++){
      float wb = cr[b];
      #pragma unroll
      for (int k=0;k<8;k++) u[b][k] += wb*bf2f(vv[k]);
    }
  }
  #pragma unroll
  for (int b=0;b<NBASE;b++){
    u16x8 o8;
    #pragma unroll
    for (int k=0;k<8;k++) o8[k] = f2bf(u[b][k]);
    *(u16x8*)(s1 + (size_t)n*(NBASE*FEAT) + b*FEAT + sl*8) = o8;
  }
}

// ---------------- fused GEMM, 2 N-halves (36KB LDS -> 4 blocks/CU) ----------------
__global__ __launch_bounds__(256, 4)
void k_gemmHD(const unsigned short* __restrict__ A0,   // s1 [MP][512]
              const unsigned short* __restrict__ A1,   // xb [MP][128]
              const unsigned short* __restrict__ B1t,  // [256][640]
              const unsigned short* __restrict__ BtV,  // [128][256]
              const float* __restrict__ bias1,
              float* __restrict__ D)                   // [MP][128]
{
  __shared__ __align__(16) unsigned short As[32*64];     // 4 KB
  __shared__ __align__(16) unsigned short Bs[128*64];    // 16 KB
  __shared__ __align__(16) unsigned short hs[32*256];    // 16 KB

  const int tid = threadIdx.x;
  const int w = tid >> 6, lane = tid & 63;
  const int wr = w >> 1, wc = w & 1;
  const int m0 = blockIdx.x * 32;

  // ---- stage 1, two N-halves ----
  for (int half=0; half<2; ++half){
    f32x4 acc[4];
    #pragma unroll
    for (int i=0;i<4;i++) acc[i] = (f32x4){0.f,0.f,0.f,0.f};
    for (int kt=0; kt<10; ++kt){
      const int kb = kt*64;
      {
        const unsigned short* Ab; int ld, kk0;
        if (kb < 512){ Ab = A0; ld = 512; kk0 = kb; } else { Ab = A1; ld = 128; kk0 = kb-512; }
        int row = tid >> 3, slot = tid & 7;
        int srcs = slot ^ (row & 7);
        load_lds16(Ab + (size_t)(m0+row)*ld + kk0 + srcs*8, (char*)As + (w*64)*16);
      }
      #pragma unroll
      for (int t=0;t<4;t++){
        int c = t*256 + tid, row = c >> 3, slot = c & 7;
        int srcs = slot ^ (row & 7);
        load_lds16(B1t + (size_t)(half*128+row)*640 + kb + srcs*8, (char*)Bs + (t*256 + w*64)*16);
      }
      asm volatile("s_waitcnt vmcnt(0)" ::: "memory");
      __syncthreads();
      #pragma unroll
      for (int kk=0;kk<2;++kk){
        int arow = wr*16 + (lane & 15);
        int aslot = (kk*4 + (lane >> 4)) ^ (arow & 7);
        bf16x8 afr = *(const bf16x8*)(As + arow*64 + aslot*8);
        #pragma unroll
        for (int fn=0;fn<4;++fn){
          int brow = wc*64 + fn*16 + (lane & 15);
          int bslot = (kk*4 + (lane >> 4)) ^ (brow & 7);
          bf16x8 bfr = *(const bf16x8*)(Bs + brow*64 + bslot*8);
          acc[fn] = __builtin_amdgcn_mfma_f32_16x16x32_bf16(afr, bfr, acc[fn], 0, 0, 0);
        }
      }
      __syncthreads();
    }
    // h half -> hs (bias + relu, bf16, octet XOR swizzle)
    #pragma unroll
    for (int fn=0;fn<4;++fn){
      int col = half*128 + wc*64 + fn*16 + (lane & 15);
      float b = bias1[col];
      int s = col >> 3;
      #pragma unroll
      for (int q=0;q<4;q++){
        int row = wr*16 + (lane >> 4)*4 + q;
        float val = acc[fn][q] + b;
        val = val > 0.f ? val : 0.f;
        int p = (s & ~7) | ((s & 7) ^ (row & 7));
        hs[row*256 + p*8 + (col & 7)] = f2bf(val);
      }
    }
  }
  __syncthreads();

  // ---- stage 2: hs [32][256] @ BtV^T -> D [32][128] ----
  f32x4 acc2[4];
  #pragma unroll
  for (int i=0;i<4;i++) acc2[i] = (f32x4){0.f,0.f,0.f,0.f};
  for (int kt=0; kt<4; ++kt){
    const int kb = kt*64;
    #pragma unroll
    for (int t=0;t<4;t++){
      int c = t*256 + tid, row = c >> 3, slot = c & 7;
      int srcs = slot ^ (row & 7);
      load_lds16(BtV + (size_t)row*256 + kb + srcs*8, (char*)Bs + (t*256 + w*64)*16);
    }
    asm volatile("s_waitcnt vmcnt(0)" ::: "memory");
    __syncthreads();
    #pragma unroll
    for (int kk=0;kk<2;++kk){
      int arow = wr*16 + (lane & 15);
      int slog = kt*8 + kk*4 + (lane >> 4);
      int ap = (slog & ~7) | ((slog & 7) ^ (arow & 7));
      bf16x8 afr = *(const bf16x8*)(hs + arow*256 + ap*8);
      #pragma unroll
      for (int fn=0;fn<4;++fn){
        int brow = wc*64 + fn*16 + (lane & 15);
        int bslot = (kk*4 + (lane >> 4)) ^ (brow & 7);
        bf16x8 bfr = *(const bf16x8*)(Bs + brow*64 + bslot*8);
        acc2[fn] = __builtin_amdgcn_mfma_f32_16x16x32_bf16(afr, bfr, acc2[fn], 0, 0, 0);
      }
    }
    __syncthreads();
  }
  #pragma unroll
  for (int fn=0;fn<4;++fn){
    int col = wc*64 + fn*16 + (lane & 15);
    #pragma unroll
    for (int q=0;q<4;q++){
      int row = m0 + wr*16 + (lane >> 4)*4 + q;
      D[(size_t)row*128 + col] = acc2[fn][q];
    }
  }
}

// score[n] = sum_e (comp2[r_e]/c_{n,r_e}) . D[src_e][4g..] + D[n][80+g]
__global__ void k_score2(const float* __restrict__ D, const int* __restrict__ cursor,
                         const unsigned int* __restrict__ spk,
                         const float* __restrict__ comp2, const int* __restrict__ batch,
                         float* __restrict__ sc){
  __shared__ float4 c2s[8];
  __shared__ float4 wc4[16*8];     // per-group combined weights comp2[r]/cnt_r
  if (threadIdx.x < 8) c2s[threadIdx.x] = ((const float4*)comp2)[threadIdx.x];
  __syncthreads();
  int grp = threadIdx.x >> 4, sl = threadIdx.x & 15;
  int n = blockIdx.x*16 + grp;
  if (n >= NNODE) return;
  int g = batch[n];
  int C = cursor[n]; if (C > PAD) C = PAD;
  const unsigned int* pp = spk + (size_t)n*PAD;
  if (sl < 8){
    int c = 0;
    for (int j=0;j<C;j++) c += (int)(((pp[j] >> 15) & 7) == (unsigned)sl);
    float inv = (c > 0) ? __builtin_amdgcn_rcpf((float)c) : 0.f;
    float4 cw = c2s[sl];
    cw.x *= inv; cw.y *= inv; cw.z *= inv; cw.w *= inv;
    wc4[grp*8 + sl] = cw;
  }
  float acc = 0.f;
  for (int j = sl; j < C; j += 16){
    unsigned int pk = pp[j];
    int s = pk & 0x7FFF;
    float4 dv = *(const float4*)(D + (size_t)s*128 + g*4);
    float4 cw = wc4[grp*8 + ((pk >> 15) & 7)];
    acc += cw.x*dv.x + cw.y*dv.y + cw.z*dv.z + cw.w*dv.w;
  }
  #pragma unroll
  for (int d=8; d; d>>=1) acc += __shfl_down(acc, d, 16);
  if (sl == 0) sc[n] = acc + D[(size_t)n*128 + 80 + g];
}

__global__ void k_lsm(const float* __restrict__ sc, float* __restrict__ out){
  __shared__ float sb[1024];
  __shared__ float red[256];
  int g = blockIdx.x, t = threadIdx.x;
  float lm = -1e30f;
  for (int j=t; j<1024; j+=256){
    float v = (j < NPG) ? sc[g*NPG + j] : -1e30f;
    sb[j] = v; lm = fmaxf(lm, v);
  }
  red[t] = lm; __syncthreads();
  for (int off=128; off; off>>=1){ if (t < off) red[t] = fmaxf(red[t], red[t+off]); __syncthreads(); }
  float mx = red[0]; __syncthreads();
  float ls = 0.f;
  for (int j=t; j<1024; j+=256){ if (j < NPG) ls += expf(sb[j] - mx); }
  red[t] = ls; __syncthreads();
  for (int off=128; off; off>>=1){ if (t < off) red[t] += red[t+off]; __syncthreads(); }
  float lse = mx + logf(red[0]);
  for (int j=t; j<NPG; j+=256) out[g*NPG + j] = sb[j] - lse;
}

// ---------------- launch ----------------
extern "C" void kernel_launch(void* const* d_in, const int* in_sizes, int n_in,
                              void* d_out, int out_size, void* d_ws, size_t ws_size,
                              hipStream_t stream) {
  const float* x       = (const float*)d_in[0];
  const float* node_x  = (const float*)d_in[2];
  const int*   ei      = (const int*)d_in[3];
  const int*   et      = (const int*)d_in[4];
  const int*   batch   = (const int*)d_in[5];
  const float* comp1   = (const float*)d_in[7];
  const float* basis1  = (const float*)d_in[8];
  const float* root1   = (const float*)d_in[9];
  const float* bias1   = (const float*)d_in[10];
  const float* comp2   = (const float*)d_in[11];
  const float* basis2  = (const float*)d_in[12];
  const float* root2   = (const float*)d_in[13];
  const float* msg_w   = (const float*)d_in[15];
  const float* msg_b   = (const float*)d_in[16];
  float* out = (float*)d_out;

  char* p = (char*)d_ws;
  size_t off = 0;
  auto alloc = [&](size_t bytes) -> char* {
    char* r = p + off;
    off += (bytes + 255) & ~(size_t)255;
    return r;
  };
  int*            cursor = (int*)alloc(NNODE*4);
  unsigned int*   spk    = (unsigned int*)alloc((size_t)NNODE*PAD*4);
  unsigned short* B1t    = (unsigned short*)alloc((size_t)256*640*2);
  unsigned short* BtV    = (unsigned short*)alloc((size_t)128*256*2);
  float*          me     = (float*)alloc(NGRAPH*EMB*4);
  float*          v      = (float*)alloc((size_t)NGRAPH*1280*4);
  unsigned short* xb     = (unsigned short*)alloc((size_t)MP*FEAT*2);
  unsigned short* s1     = (unsigned short*)alloc((size_t)MP*512*2);
  float*          D      = (float*)alloc((size_t)MP*128*4);
  float*          sc     = (float*)alloc(NNODE*4);

  k_zeroMe     <<<89, 256, 0, stream>>>(cursor, x, msg_w, msg_b, me);
  k_prepScatter<<<10790, 256, 0, stream>>>(ei, et, cursor, spk, node_x, xb,
                                           basis1, root1, B1t, basis2, root2, me, v);
  k_agg1  <<<1378, 256, 0, stream>>>(xb, cursor, spk, comp1, s1, v, BtV);
  k_gemmHD<<<628, 256, 0, stream>>>(s1, xb, B1t, BtV, bias1, D);
  k_score2<<<1250, 256, 0, stream>>>(D, cursor, spk, comp2, batch, sc);
  k_lsm   <<<NGRAPH, 256, 0, stream>>>(sc, out);
}

// Round 19
// 99.527 us; speedup vs baseline: 1.0585x; 1.0585x over previous
//
#include <hip/hip_runtime.h>
#include <hip/hip_bf16.h>

#define NEDGE 320000
#define NNODE 20000
#define MP    20096      // 628*32 padded rows
#define NRELS 8
#define FEAT  128
#define HID   256
#define EMB   128
#define NGRAPH 20
#define NPG   1000
#define NBASE 4
#define PAD   96         // max degree slack (Poisson(16), P(deg>=96) ~ 1e-40)

typedef __attribute__((ext_vector_type(4))) float f32x4;
typedef __attribute__((ext_vector_type(8))) __bf16 bf16x8;
typedef __attribute__((ext_vector_type(8))) unsigned short u16x8;

static __device__ __forceinline__ float bf2f(unsigned short u){
  union { unsigned int i; float f; } v; v.i = ((unsigned int)u) << 16; return v.f;
}
static __device__ __forceinline__ unsigned short f2bf(float f){
  union { float f; unsigned int i; } v; v.f = f;
  unsigned int x = v.i;
  return (unsigned short)((x + 0x7fffu + ((x >> 16) & 1u)) >> 16);
}

__device__ __forceinline__ void load_lds16(const void* g, void* l){
  __builtin_amdgcn_global_load_lds((const __attribute__((address_space(1))) void*)g,
                                   (__attribute__((address_space(3))) void*)l, 16, 0, 0);
}

// ---------------- init: zero per-node cursor + me ----------------
__global__ void k_zeroMe(int* __restrict__ cursor,
                         const float* __restrict__ x, const float* __restrict__ mw,
                         const float* __restrict__ mb, float* __restrict__ me){
  int blk = blockIdx.x;
  if (blk < 79){
    int i = blk*256 + threadIdx.x;
    if (i < NNODE) cursor[i] = 0;
  } else {
    int id = (blk-79)*256 + threadIdx.x;
    if (id >= NGRAPH*EMB) return;
    int g = id >> 7, e = id & 127;
    float s = mb[e];
    for (int i=0;i<HID;i++) s += x[g*HID + i] * mw[i*EMB + e];
    me[id] = s;
  }
}

// ---------------- fused direct-slot scatter + weight prep ----------------
// blocks [0,1250): scatter ; [1250,3750): xb cvt (float4) ; [3750,4390): B1t ; [4390,10790): v
__global__ void k_prepScatter(const int* __restrict__ ei, const int* __restrict__ et,
                              int* __restrict__ cursor, unsigned int* __restrict__ spk,
                              const float* __restrict__ xin, unsigned short* __restrict__ xb,
                              const float* __restrict__ basis, const float* __restrict__ root,
                              unsigned short* __restrict__ Bt,
                              const float* __restrict__ basis2, const float* __restrict__ root2,
                              const float* __restrict__ me, float* __restrict__ v){
  int blk = blockIdx.x;
  if (blk < 1250){
    int e = blk*256 + threadIdx.x;
    if (e < NEDGE){
      int src = ei[e];
      int r = et[e];
      int dst = ei[NEDGE + e];
      int pos = atomicAdd(&cursor[dst], 1);
      if (pos < PAD) spk[(size_t)dst*PAD + pos] = (unsigned int)src | ((unsigned int)r << 15);
    }
  } else if (blk < 3750){
    int i = (blk-1250)*1024 + threadIdx.x*4;
    if (i < NNODE*FEAT){
      float4 f = *(const float4*)(xin + i);
      ushort4 o;
      o.x = f2bf(f.x); o.y = f2bf(f.y); o.z = f2bf(f.z); o.w = f2bf(f.w);
      *(ushort4*)(xb + i) = o;
    }
  } else if (blk < 4390){
    int idx = (blk-3750)*256 + threadIdx.x;
    if (idx >= 256*640) return;
    int o = idx / 640, k = idx % 640;
    float val = (k < 512) ? basis[(size_t)k*256 + o] : root[(size_t)(k-512)*256 + o];
    Bt[(size_t)o*640 + k] = f2bf(val);
  } else {
    int w = threadIdx.x >> 6, lane = threadIdx.x & 63;
    int id = (blk-4390)*4 + w;
    if (id >= NGRAPH*1280) return;
    int g = id / 1280, k = id % 1280;
    const float* row = (k < 1024) ? (basis2 + (size_t)k*EMB) : (root2 + (size_t)(k-1024)*EMB);
    float2 a = *(const float2*)(row + lane*2);
    float2 m = *(const float2*)(me + g*EMB + lane*2);
    float p = a.x*m.x + a.y*m.y;
    #pragma unroll
    for (int d=32; d; d>>=1) p += __shfl_down(p, d);
    if (lane == 0) v[(size_t)g*1280 + k] = p;
  }
}

// ---------------- layer1 aggregation (16-lane groups, 8-deep load batch) + packV ----------------
__global__ void k_agg1(const unsigned short* __restrict__ xb, const int* __restrict__ cursor,
                       const unsigned int* __restrict__ spk,
                       const float* __restrict__ comp1, unsigned short* __restrict__ s1,
                       const float* __restrict__ v, unsigned short* __restrict__ BtV){
  if (blockIdx.x >= 1250){
    int idx = (blockIdx.x-1250)*256 + threadIdx.x;
    if (idx >= 128*256) return;
    int c = idx >> 8, k = idx & 255;
    float val = 0.f;
    if (c < 80)        val = v[(size_t)(c>>2)*1280 + (c&3)*256 + k];
    else if (c < 100)  val = v[(size_t)(c-80)*1280 + 1024 + k];
    BtV[idx] = f2bf(val);
    return;
  }
  __shared__ float c1s[32];
  __shared__ float wcomb[16*32];   // per-group combined weights comp1[r][b]/cnt_r
  if (threadIdx.x < 32) c1s[threadIdx.x] = comp1[threadIdx.x];
  __syncthreads();
  int grp = threadIdx.x >> 4, sl = threadIdx.x & 15;
  int n = blockIdx.x*16 + grp;
  int C = cursor[n]; if (C > PAD) C = PAD;
  const unsigned int* pp = spk + (size_t)n*PAD;
  // pre-pass: lanes 0..7 count their rel, write combined weights (wave-coherent LDS)
  if (sl < 8){
    int c = 0;
    for (int j=0;j<C;j++) c += (int)(((pp[j] >> 15) & 7) == (unsigned)sl);
    float inv = (c > 0) ? __builtin_amdgcn_rcpf((float)c) : 0.f;
    #pragma unroll
    for (int b=0;b<NBASE;b++) wcomb[grp*32 + sl*4 + b] = c1s[sl*4+b]*inv;
  }
  const float* wg = wcomb + grp*32;
  float u[NBASE][8] = {};
  int j = 0;
  for (; j+8 <= C; j += 8){
    unsigned int pk[8];
    u16x8 vv[8];
    #pragma unroll
    for (int t=0;t<8;t++) pk[t] = pp[j+t];
    #pragma unroll
    for (int t=0;t<8;t++) vv[t] = *(const u16x8*)(xb + (size_t)(pk[t] & 0x7FFF)*FEAT + sl*8);
    #pragma unroll
    for (int t=0;t<8;t++){
      const float* cr = wg + ((pk[t] >> 15) & 7)*4;
      #pragma unroll
      for (int b=0;b<NBASE;b++){
        float wb = cr[b];
        #pragma unroll
        for (int k=0;k<8;k++) u[b][k] += wb*bf2f(vv[t][k]);
      }
    }
  }
  for (; j < C; ++j){
    unsigned int pk = pp[j];
    u16x8 vv = *(const u16x8*)(xb + (size_t)(pk & 0x7FFF)*FEAT + sl*8);
    const float* cr = wg + ((pk >> 15) & 7)*4;
    #pragma unroll
    for (int b=0;b<NBASE;b++){
      float wb = cr[b];
      #pragma unroll
      for (int k=0;k<8;k++) u[b][k] += wb*bf2f(vv[k]);
    }
  }
  #pragma unroll
  for (int b=0;b<NBASE;b++){
    u16x8 o8;
    #pragma unroll
    for (int k=0;k<8;k++) o8[k] = f2bf(u[b][k]);
    *(u16x8*)(s1 + (size_t)n*(NBASE*FEAT) + b*FEAT + sl*8) = o8;
  }
}

// ---------------- fused GEMM, 2 N-halves (36KB LDS -> 4 blocks/CU) ----------------
__global__ __launch_bounds__(256, 4)
void k_gemmHD(const unsigned short* __restrict__ A0,   // s1 [MP][512]
              const unsigned short* __restrict__ A1,   // xb [MP][128]
              const unsigned short* __restrict__ B1t,  // [256][640]
              const unsigned short* __restrict__ BtV,  // [128][256]
              const float* __restrict__ bias1,
              float* __restrict__ D)                   // [MP][128]
{
  __shared__ __align__(16) unsigned short As[32*64];     // 4 KB
  __shared__ __align__(16) unsigned short Bs[128*64];    // 16 KB
  __shared__ __align__(16) unsigned short hs[32*256];    // 16 KB

  const int tid = threadIdx.x;
  const int w = tid >> 6, lane = tid & 63;
  const int wr = w >> 1, wc = w & 1;
  const int m0 = blockIdx.x * 32;

  // ---- stage 1, two N-halves ----
  for (int half=0; half<2; ++half){
    f32x4 acc[4];
    #pragma unroll
    for (int i=0;i<4;i++) acc[i] = (f32x4){0.f,0.f,0.f,0.f};
    for (int kt=0; kt<10; ++kt){
      const int kb = kt*64;
      {
        const unsigned short* Ab; int ld, kk0;
        if (kb < 512){ Ab = A0; ld = 512; kk0 = kb; } else { Ab = A1; ld = 128; kk0 = kb-512; }
        int row = tid >> 3, slot = tid & 7;
        int srcs = slot ^ (row & 7);
        load_lds16(Ab + (size_t)(m0+row)*ld + kk0 + srcs*8, (char*)As + (w*64)*16);
      }
      #pragma unroll
      for (int t=0;t<4;t++){
        int c = t*256 + tid, row = c >> 3, slot = c & 7;
        int srcs = slot ^ (row & 7);
        load_lds16(B1t + (size_t)(half*128+row)*640 + kb + srcs*8, (char*)Bs + (t*256 + w*64)*16);
      }
      asm volatile("s_waitcnt vmcnt(0)" ::: "memory");
      __syncthreads();
      #pragma unroll
      for (int kk=0;kk<2;++kk){
        int arow = wr*16 + (lane & 15);
        int aslot = (kk*4 + (lane >> 4)) ^ (arow & 7);
        bf16x8 afr = *(const bf16x8*)(As + arow*64 + aslot*8);
        #pragma unroll
        for (int fn=0;fn<4;++fn){
          int brow = wc*64 + fn*16 + (lane & 15);
          int bslot = (kk*4 + (lane >> 4)) ^ (brow & 7);
          bf16x8 bfr = *(const bf16x8*)(Bs + brow*64 + bslot*8);
          acc[fn] = __builtin_amdgcn_mfma_f32_16x16x32_bf16(afr, bfr, acc[fn], 0, 0, 0);
        }
      }
      __syncthreads();
    }
    // h half -> hs (bias + relu, bf16, octet XOR swizzle)
    #pragma unroll
    for (int fn=0;fn<4;++fn){
      int col = half*128 + wc*64 + fn*16 + (lane & 15);
      float b = bias1[col];
      int s = col >> 3;
      #pragma unroll
      for (int q=0;q<4;q++){
        int row = wr*16 + (lane >> 4)*4 + q;
        float val = acc[fn][q] + b;
        val = val > 0.f ? val : 0.f;
        int p = (s & ~7) | ((s & 7) ^ (row & 7));
        hs[row*256 + p*8 + (col & 7)] = f2bf(val);
      }
    }
  }
  __syncthreads();

  // ---- stage 2: hs [32][256] @ BtV^T -> D [32][128] ----
  f32x4 acc2[4];
  #pragma unroll
  for (int i=0;i<4;i++) acc2[i] = (f32x4){0.f,0.f,0.f,0.f};
  for (int kt=0; kt<4; ++kt){
    const int kb = kt*64;
    #pragma unroll
    for (int t=0;t<4;t++){
      int c = t*256 + tid, row = c >> 3, slot = c & 7;
      int srcs = slot ^ (row & 7);
      load_lds16(BtV + (size_t)row*256 + kb + srcs*8, (char*)Bs + (t*256 + w*64)*16);
    }
    asm volatile("s_waitcnt vmcnt(0)" ::: "memory");
    __syncthreads();
    #pragma unroll
    for (int kk=0;kk<2;++kk){
      int arow = wr*16 + (lane & 15);
      int slog = kt*8 + kk*4 + (lane >> 4);
      int ap = (slog & ~7) | ((slog & 7) ^ (arow & 7));
      bf16x8 afr = *(const bf16x8*)(hs + arow*256 + ap*8);
      #pragma unroll
      for (int fn=0;fn<4;++fn){
        int brow = wc*64 + fn*16 + (lane & 15);
        int bslot = (kk*4 + (lane >> 4)) ^ (brow & 7);
        bf16x8 bfr = *(const bf16x8*)(Bs + brow*64 + bslot*8);
        acc2[fn] = __builtin_amdgcn_mfma_f32_16x16x32_bf16(afr, bfr, acc2[fn], 0, 0, 0);
      }
    }
    __syncthreads();
  }
  #pragma unroll
  for (int fn=0;fn<4;++fn){
    int col = wc*64 + fn*16 + (lane & 15);
    #pragma unroll
    for (int q=0;q<4;q++){
      int row = m0 + wr*16 + (lane >> 4)*4 + q;
      D[(size_t)row*128 + col] = acc2[fn][q];
    }
  }
}

// score[n] = sum_e (comp2[r_e]/c_{n,r_e}) . D[src_e][4g..] + D[n][80+g]
__global__ void k_score2(const float* __restrict__ D, const int* __restrict__ cursor,
                         const unsigned int* __restrict__ spk,
                         const float* __restrict__ comp2, const int* __restrict__ batch,
                         float* __restrict__ sc){
  __shared__ float4 c2s[8];
  __shared__ float4 wc4[16*8];     // per-group combined weights comp2[r]/cnt_r
  if (threadIdx.x < 8) c2s[threadIdx.x] = ((const float4*)comp2)[threadIdx.x];
  __syncthreads();
  int grp = threadIdx.x >> 4, sl = threadIdx.x & 15;
  int n = blockIdx.x*16 + grp;
  if (n >= NNODE) return;
  int g = batch[n];
  int C = cursor[n]; if (C > PAD) C = PAD;
  const unsigned int* pp = spk + (size_t)n*PAD;
  if (sl < 8){
    int c = 0;
    for (int j=0;j<C;j++) c += (int)(((pp[j] >> 15) & 7) == (unsigned)sl);
    float inv = (c > 0) ? __builtin_amdgcn_rcpf((float)c) : 0.f;
    float4 cw = c2s[sl];
    cw.x *= inv; cw.y *= inv; cw.z *= inv; cw.w *= inv;
    wc4[grp*8 + sl] = cw;
  }
  float acc = 0.f;
  for (int j = sl; j < C; j += 16){
    unsigned int pk = pp[j];
    int s = pk & 0x7FFF;
    float4 dv = *(const float4*)(D + (size_t)s*128 + g*4);
    float4 cw = wc4[grp*8 + ((pk >> 15) & 7)];
    acc += cw.x*dv.x + cw.y*dv.y + cw.z*dv.z + cw.w*dv.w;
  }
  #pragma unroll
  for (int d=8; d; d>>=1) acc += __shfl_down(acc, d, 16);
  if (sl == 0) sc[n] = acc + D[(size_t)n*128 + 80 + g];
}

__global__ void k_lsm(const float* __restrict__ sc, float* __restrict__ out){
  __shared__ float sb[1024];
  __shared__ float red[256];
  int g = blockIdx.x, t = threadIdx.x;
  float lm = -1e30f;
  for (int j=t; j<1024; j+=256){
    float v = (j < NPG) ? sc[g*NPG + j] : -1e30f;
    sb[j] = v; lm = fmaxf(lm, v);
  }
  red[t] = lm; __syncthreads();
  for (int off=128; off; off>>=1){ if (t < off) red[t] = fmaxf(red[t], red[t+off]); __syncthreads(); }
  float mx = red[0]; __syncthreads();
  float ls = 0.f;
  for (int j=t; j<1024; j+=256){ if (j < NPG) ls += expf(sb[j] - mx); }
  red[t] = ls; __syncthreads();
  for (int off=128; off; off>>=1){ if (t < off) red[t] += red[t+off]; __syncthreads(); }
  float lse = mx + logf(red[0]);
  for (int j=t; j<NPG; j+=256) out[g*NPG + j] = sb[j] - lse;
}

// ---------------- launch ----------------
extern "C" void kernel_launch(void* const* d_in, const int* in_sizes, int n_in,
                              void* d_out, int out_size, void* d_ws, size_t ws_size,
                              hipStream_t stream) {
  const float* x       = (const float*)d_in[0];
  const float* node_x  = (const float*)d_in[2];
  const int*   ei      = (const int*)d_in[3];
  const int*   et      = (const int*)d_in[4];
  const int*   batch   = (const int*)d_in[5];
  const float* comp1   = (const float*)d_in[7];
  const float* basis1  = (const float*)d_in[8];
  const float* root1   = (const float*)d_in[9];
  const float* bias1   = (const float*)d_in[10];
  const float* comp2   = (const float*)d_in[11];
  const float* basis2  = (const float*)d_in[12];
  const float* root2   = (const float*)d_in[13];
  const float* msg_w   = (const float*)d_in[15];
  const float* msg_b   = (const float*)d_in[16];
  float* out = (float*)d_out;

  char* p = (char*)d_ws;
  size_t off = 0;
  auto alloc = [&](size_t bytes) -> char* {
    char* r = p + off;
    off += (bytes + 255) & ~(size_t)255;
    return r;
  };
  int*            cursor = (int*)alloc(NNODE*4);
  unsigned int*   spk    = (unsigned int*)alloc((size_t)NNODE*PAD*4);
  unsigned short* B1t    = (unsigned short*)alloc((size_t)256*640*2);
  unsigned short* BtV    = (unsigned short*)alloc((size_t)128*256*2);
  float*          me     = (float*)alloc(NGRAPH*EMB*4);
  float*          v      = (float*)alloc((size_t)NGRAPH*1280*4);
  unsigned short* xb     = (unsigned short*)alloc((size_t)MP*FEAT*2);
  unsigned short* s1     = (unsigned short*)alloc((size_t)MP*512*2);
  float*          D      = (float*)alloc((size_t)MP*128*4);
  float*          sc     = (float*)alloc(NNODE*4);

  k_zeroMe     <<<89, 256, 0, stream>>>(cursor, x, msg_w, msg_b, me);
  k_prepScatter<<<10790, 256, 0, stream>>>(ei, et, cursor, spk, node_x, xb,
                                           basis1, root1, B1t, basis2, root2, me, v);
  k_agg1  <<<1378, 256, 0, stream>>>(xb, cursor, spk, comp1, s1, v, BtV);
  k_gemmHD<<<628, 256, 0, stream>>>(s1, xb, B1t, BtV, bias1, D);
  k_score2<<<1250, 256, 0, stream>>>(D, cursor, spk, comp2, batch, sc);
  k_lsm   <<<NGRAPH, 256, 0, stream>>>(sc, out);
}

// Round 20
// 99.013 us; speedup vs baseline: 1.0640x; 1.0052x over previous
//
#include <hip/hip_runtime.h>
#include <hip/hip_bf16.h>

#define NEDGE 320000
#define NNODE 20000
#define MP    20096      // 628*32 padded rows
#define NRELS 8
#define FEAT  128
#define HID   256
#define EMB   128
#define NGRAPH 20
#define NPG   1000
#define NBASE 4
#define PAD   96         // max degree slack (Poisson(16), P(deg>=96) ~ 1e-40)

typedef __attribute__((ext_vector_type(4))) float f32x4;
typedef __attribute__((ext_vector_type(8))) __bf16 bf16x8;
typedef __attribute__((ext_vector_type(8))) unsigned short u16x8;

static __device__ __forceinline__ float bf2f(unsigned short u){
  union { unsigned int i; float f; } v; v.i = ((unsigned int)u) << 16; return v.f;
}
static __device__ __forceinline__ unsigned short f2bf(float f){
  union { float f; unsigned int i; } v; v.f = f;
  unsigned int x = v.i;
  return (unsigned short)((x + 0x7fffu + ((x >> 16) & 1u)) >> 16);
}

__device__ __forceinline__ void load_lds16(const void* g, void* l){
  __builtin_amdgcn_global_load_lds((const __attribute__((address_space(1))) void*)g,
                                   (__attribute__((address_space(3))) void*)l, 16, 0, 0);
}

// ---------------- init: zero per-node cursor + me ----------------
__global__ void k_zeroMe(int* __restrict__ cursor,
                         const float* __restrict__ x, const float* __restrict__ mw,
                         const float* __restrict__ mb, float* __restrict__ me){
  int blk = blockIdx.x;
  if (blk < 79){
    int i = blk*256 + threadIdx.x;
    if (i < NNODE) cursor[i] = 0;
  } else {
    int id = (blk-79)*256 + threadIdx.x;
    if (id >= NGRAPH*EMB) return;
    int g = id >> 7, e = id & 127;
    float s = mb[e];
    for (int i=0;i<HID;i++) s += x[g*HID + i] * mw[i*EMB + e];
    me[id] = s;
  }
}

// ---------------- fused direct-slot scatter + weight prep ----------------
// blocks [0,1250): scatter ; [1250,3750): xb cvt (float4) ; [3750,4390): B1t ; [4390,10790): v
__global__ void k_prepScatter(const int* __restrict__ ei, const int* __restrict__ et,
                              int* __restrict__ cursor, unsigned int* __restrict__ spk,
                              const float* __restrict__ xin, unsigned short* __restrict__ xb,
                              const float* __restrict__ basis, const float* __restrict__ root,
                              unsigned short* __restrict__ Bt,
                              const float* __restrict__ basis2, const float* __restrict__ root2,
                              const float* __restrict__ me, float* __restrict__ v){
  int blk = blockIdx.x;
  if (blk < 1250){
    int e = blk*256 + threadIdx.x;
    if (e < NEDGE){
      int src = ei[e];
      int r = et[e];
      int dst = ei[NEDGE + e];
      int pos = atomicAdd(&cursor[dst], 1);
      if (pos < PAD) spk[(size_t)dst*PAD + pos] = (unsigned int)src | ((unsigned int)r << 15);
    }
  } else if (blk < 3750){
    int i = (blk-1250)*1024 + threadIdx.x*4;
    if (i < NNODE*FEAT){
      float4 f = *(const float4*)(xin + i);
      ushort4 o;
      o.x = f2bf(f.x); o.y = f2bf(f.y); o.z = f2bf(f.z); o.w = f2bf(f.w);
      *(ushort4*)(xb + i) = o;
    }
  } else if (blk < 4390){
    int idx = (blk-3750)*256 + threadIdx.x;
    if (idx >= 256*640) return;
    int o = idx / 640, k = idx % 640;
    float val = (k < 512) ? basis[(size_t)k*256 + o] : root[(size_t)(k-512)*256 + o];
    Bt[(size_t)o*640 + k] = f2bf(val);
  } else {
    int w = threadIdx.x >> 6, lane = threadIdx.x & 63;
    int id = (blk-4390)*4 + w;
    if (id >= NGRAPH*1280) return;
    int g = id / 1280, k = id % 1280;
    const float* row = (k < 1024) ? (basis2 + (size_t)k*EMB) : (root2 + (size_t)(k-1024)*EMB);
    float2 a = *(const float2*)(row + lane*2);
    float2 m = *(const float2*)(me + g*EMB + lane*2);
    float p = a.x*m.x + a.y*m.y;
    #pragma unroll
    for (int d=32; d; d>>=1) p += __shfl_down(p, d);
    if (lane == 0) v[(size_t)g*1280 + k] = p;
  }
}

// ---------------- layer1 aggregation (16-lane groups, 8-deep load batch) + packV ----------------
__global__ void k_agg1(const unsigned short* __restrict__ xb, const int* __restrict__ cursor,
                       const unsigned int* __restrict__ spk,
                       const float* __restrict__ comp1, unsigned short* __restrict__ s1,
                       const float* __restrict__ v, unsigned short* __restrict__ BtV){
  if (blockIdx.x >= 1250){
    int idx = (blockIdx.x-1250)*256 + threadIdx.x;
    if (idx >= 128*256) return;
    int c = idx >> 8, k = idx & 255;
    float val = 0.f;
    if (c < 80)        val = v[(size_t)(c>>2)*1280 + (c&3)*256 + k];
    else if (c < 100)  val = v[(size_t)(c-80)*1280 + 1024 + k];
    BtV[idx] = f2bf(val);
    return;
  }
  __shared__ float c1s[32];
  __shared__ float wcomb[16*32];   // per-group combined weights comp1[r][b]/cnt_r
  if (threadIdx.x < 32) c1s[threadIdx.x] = comp1[threadIdx.x];
  __syncthreads();
  int grp = threadIdx.x >> 4, sl = threadIdx.x & 15;
  int n = blockIdx.x*16 + grp;
  int C = cursor[n]; if (C > PAD) C = PAD;
  const unsigned int* pp = spk + (size_t)n*PAD;
  // pre-pass: lanes 0..7 count their rel, write combined weights (wave-coherent LDS)
  if (sl < 8){
    int c = 0;
    for (int j=0;j<C;j++) c += (int)(((pp[j] >> 15) & 7) == (unsigned)sl);
    float inv = (c > 0) ? __builtin_amdgcn_rcpf((float)c) : 0.f;
    #pragma unroll
    for (int b=0;b<NBASE;b++) wcomb[grp*32 + sl*4 + b] = c1s[sl*4+b]*inv;
  }
  const float* wg = wcomb + grp*32;
  float u[NBASE][8] = {};
  int j = 0;
  for (; j+8 <= C; j += 8){
    unsigned int pk[8];
    u16x8 vv[8];
    #pragma unroll
    for (int t=0;t<8;t++) pk[t] = pp[j+t];
    #pragma unroll
    for (int t=0;t<8;t++) vv[t] = *(const u16x8*)(xb + (size_t)(pk[t] & 0x7FFF)*FEAT + sl*8);
    #pragma unroll
    for (int t=0;t<8;t++){
      const float* cr = wg + ((pk[t] >> 15) & 7)*4;
      #pragma unroll
      for (int b=0;b<NBASE;b++){
        float wb = cr[b];
        #pragma unroll
        for (int k=0;k<8;k++) u[b][k] += wb*bf2f(vv[t][k]);
      }
    }
  }
  for (; j < C; ++j){
    unsigned int pk = pp[j];
    u16x8 vv = *(const u16x8*)(xb + (size_t)(pk & 0x7FFF)*FEAT + sl*8);
    const float* cr = wg + ((pk >> 15) & 7)*4;
    #pragma unroll
    for (int b=0;b<NBASE;b++){
      float wb = cr[b];
      #pragma unroll
      for (int k=0;k<8;k++) u[b][k] += wb*bf2f(vv[k]);
    }
  }
  #pragma unroll
  for (int b=0;b<NBASE;b++){
    u16x8 o8;
    #pragma unroll
    for (int k=0;k<8;k++) o8[k] = f2bf(u[b][k]);
    *(u16x8*)(s1 + (size_t)n*(NBASE*FEAT) + b*FEAT + sl*8) = o8;
  }
}

// ---------------- fused GEMM, 2 N-halves (36KB LDS -> 4 blocks/CU), D in bf16 ----------------
__global__ __launch_bounds__(256, 4)
void k_gemmHD(const unsigned short* __restrict__ A0,   // s1 [MP][512]
              const unsigned short* __restrict__ A1,   // xb [MP][128]
              const unsigned short* __restrict__ B1t,  // [256][640]
              const unsigned short* __restrict__ BtV,  // [128][256]
              const float* __restrict__ bias1,
              unsigned short* __restrict__ D)          // [MP][128] bf16
{
  __shared__ __align__(16) unsigned short As[32*64];     // 4 KB
  __shared__ __align__(16) unsigned short Bs[128*64];    // 16 KB
  __shared__ __align__(16) unsigned short hs[32*256];    // 16 KB

  const int tid = threadIdx.x;
  const int w = tid >> 6, lane = tid & 63;
  const int wr = w >> 1, wc = w & 1;
  const int m0 = blockIdx.x * 32;

  // ---- stage 1, two N-halves ----
  for (int half=0; half<2; ++half){
    f32x4 acc[4];
    #pragma unroll
    for (int i=0;i<4;i++) acc[i] = (f32x4){0.f,0.f,0.f,0.f};
    for (int kt=0; kt<10; ++kt){
      const int kb = kt*64;
      {
        const unsigned short* Ab; int ld, kk0;
        if (kb < 512){ Ab = A0; ld = 512; kk0 = kb; } else { Ab = A1; ld = 128; kk0 = kb-512; }
        int row = tid >> 3, slot = tid & 7;
        int srcs = slot ^ (row & 7);
        load_lds16(Ab + (size_t)(m0+row)*ld + kk0 + srcs*8, (char*)As + (w*64)*16);
      }
      #pragma unroll
      for (int t=0;t<4;t++){
        int c = t*256 + tid, row = c >> 3, slot = c & 7;
        int srcs = slot ^ (row & 7);
        load_lds16(B1t + (size_t)(half*128+row)*640 + kb + srcs*8, (char*)Bs + (t*256 + w*64)*16);
      }
      asm volatile("s_waitcnt vmcnt(0)" ::: "memory");
      __syncthreads();
      #pragma unroll
      for (int kk=0;kk<2;++kk){
        int arow = wr*16 + (lane & 15);
        int aslot = (kk*4 + (lane >> 4)) ^ (arow & 7);
        bf16x8 afr = *(const bf16x8*)(As + arow*64 + aslot*8);
        #pragma unroll
        for (int fn=0;fn<4;++fn){
          int brow = wc*64 + fn*16 + (lane & 15);
          int bslot = (kk*4 + (lane >> 4)) ^ (brow & 7);
          bf16x8 bfr = *(const bf16x8*)(Bs + brow*64 + bslot*8);
          acc[fn] = __builtin_amdgcn_mfma_f32_16x16x32_bf16(afr, bfr, acc[fn], 0, 0, 0);
        }
      }
      __syncthreads();
    }
    // h half -> hs (bias + relu, bf16, octet XOR swizzle)
    #pragma unroll
    for (int fn=0;fn<4;++fn){
      int col = half*128 + wc*64 + fn*16 + (lane & 15);
      float b = bias1[col];
      int s = col >> 3;
      #pragma unroll
      for (int q=0;q<4;q++){
        int row = wr*16 + (lane >> 4)*4 + q;
        float val = acc[fn][q] + b;
        val = val > 0.f ? val : 0.f;
        int p = (s & ~7) | ((s & 7) ^ (row & 7));
        hs[row*256 + p*8 + (col & 7)] = f2bf(val);
      }
    }
  }
  __syncthreads();

  // ---- stage 2: hs [32][256] @ BtV^T -> D [32][128] bf16 ----
  f32x4 acc2[4];
  #pragma unroll
  for (int i=0;i<4;i++) acc2[i] = (f32x4){0.f,0.f,0.f,0.f};
  for (int kt=0; kt<4; ++kt){
    const int kb = kt*64;
    #pragma unroll
    for (int t=0;t<4;t++){
      int c = t*256 + tid, row = c >> 3, slot = c & 7;
      int srcs = slot ^ (row & 7);
      load_lds16(BtV + (size_t)row*256 + kb + srcs*8, (char*)Bs + (t*256 + w*64)*16);
    }
    asm volatile("s_waitcnt vmcnt(0)" ::: "memory");
    __syncthreads();
    #pragma unroll
    for (int kk=0;kk<2;++kk){
      int arow = wr*16 + (lane & 15);
      int slog = kt*8 + kk*4 + (lane >> 4);
      int ap = (slog & ~7) | ((slog & 7) ^ (arow & 7));
      bf16x8 afr = *(const bf16x8*)(hs + arow*256 + ap*8);
      #pragma unroll
      for (int fn=0;fn<4;++fn){
        int brow = wc*64 + fn*16 + (lane & 15);
        int bslot = (kk*4 + (lane >> 4)) ^ (brow & 7);
        bf16x8 bfr = *(const bf16x8*)(Bs + brow*64 + bslot*8);
        acc2[fn] = __builtin_amdgcn_mfma_f32_16x16x32_bf16(afr, bfr, acc2[fn], 0, 0, 0);
      }
    }
    __syncthreads();
  }
  #pragma unroll
  for (int fn=0;fn<4;++fn){
    int col = wc*64 + fn*16 + (lane & 15);
    #pragma unroll
    for (int q=0;q<4;q++){
      int row = m0 + wr*16 + (lane >> 4)*4 + q;
      D[(size_t)row*128 + col] = f2bf(acc2[fn][q]);
    }
  }
}

// score[n] = sum_e (comp2[r_e]/c_{n,r_e}) . D[src_e][4g..] + D[n][80+g]   (D bf16, 8B/edge)
__global__ void k_score2(const unsigned short* __restrict__ D, const int* __restrict__ cursor,
                         const unsigned int* __restrict__ spk,
                         const float* __restrict__ comp2, const int* __restrict__ batch,
                         float* __restrict__ sc){
  __shared__ float4 c2s[8];
  __shared__ float4 wc4[16*8];     // per-group combined weights comp2[r]/cnt_r
  if (threadIdx.x < 8) c2s[threadIdx.x] = ((const float4*)comp2)[threadIdx.x];
  __syncthreads();
  int grp = threadIdx.x >> 4, sl = threadIdx.x & 15;
  int n = blockIdx.x*16 + grp;
  if (n >= NNODE) return;
  int g = batch[n];
  int C = cursor[n]; if (C > PAD) C = PAD;
  const unsigned int* pp = spk + (size_t)n*PAD;
  if (sl < 8){
    int c = 0;
    for (int j=0;j<C;j++) c += (int)(((pp[j] >> 15) & 7) == (unsigned)sl);
    float inv = (c > 0) ? __builtin_amdgcn_rcpf((float)c) : 0.f;
    float4 cw = c2s[sl];
    cw.x *= inv; cw.y *= inv; cw.z *= inv; cw.w *= inv;
    wc4[grp*8 + sl] = cw;
  }
  float acc = 0.f;
  for (int j = sl; j < C; j += 16){
    unsigned int pk = pp[j];
    int s = pk & 0x7FFF;
    ushort4 dv = *(const ushort4*)(D + (size_t)s*128 + g*4);
    float4 cw = wc4[grp*8 + ((pk >> 15) & 7)];
    acc += cw.x*bf2f(dv.x) + cw.y*bf2f(dv.y) + cw.z*bf2f(dv.z) + cw.w*bf2f(dv.w);
  }
  #pragma unroll
  for (int d=8; d; d>>=1) acc += __shfl_down(acc, d, 16);
  if (sl == 0) sc[n] = acc + bf2f(D[(size_t)n*128 + 80 + g]);
}

__global__ void k_lsm(const float* __restrict__ sc, float* __restrict__ out){
  __shared__ float sb[1024];
  __shared__ float red[256];
  int g = blockIdx.x, t = threadIdx.x;
  float lm = -1e30f;
  for (int j=t; j<1024; j+=256){
    float v = (j < NPG) ? sc[g*NPG + j] : -1e30f;
    sb[j] = v; lm = fmaxf(lm, v);
  }
  red[t] = lm; __syncthreads();
  for (int off=128; off; off>>=1){ if (t < off) red[t] = fmaxf(red[t], red[t+off]); __syncthreads(); }
  float mx = red[0]; __syncthreads();
  float ls = 0.f;
  for (int j=t; j<1024; j+=256){ if (j < NPG) ls += expf(sb[j] - mx); }
  red[t] = ls; __syncthreads();
  for (int off=128; off; off>>=1){ if (t < off) red[t] += red[t+off]; __syncthreads(); }
  float lse = mx + logf(red[0]);
  for (int j=t; j<NPG; j+=256) out[g*NPG + j] = sb[j] - lse;
}

// ---------------- launch ----------------
extern "C" void kernel_launch(void* const* d_in, const int* in_sizes, int n_in,
                              void* d_out, int out_size, void* d_ws, size_t ws_size,
                              hipStream_t stream) {
  const float* x       = (const float*)d_in[0];
  const float* node_x  = (const float*)d_in[2];
  const int*   ei      = (const int*)d_in[3];
  const int*   et      = (const int*)d_in[4];
  const int*   batch   = (const int*)d_in[5];
  const float* comp1   = (const float*)d_in[7];
  const float* basis1  = (const float*)d_in[8];
  const float* root1   = (const float*)d_in[9];
  const float* bias1   = (const float*)d_in[10];
  const float* comp2   = (const float*)d_in[11];
  const float* basis2  = (const float*)d_in[12];
  const float* root2   = (const float*)d_in[13];
  const float* msg_w   = (const float*)d_in[15];
  const float* msg_b   = (const float*)d_in[16];
  float* out = (float*)d_out;

  char* p = (char*)d_ws;
  size_t off = 0;
  auto alloc = [&](size_t bytes) -> char* {
    char* r = p + off;
    off += (bytes + 255) & ~(size_t)255;
    return r;
  };
  int*            cursor = (int*)alloc(NNODE*4);
  unsigned int*   spk    = (unsigned int*)alloc((size_t)NNODE*PAD*4);
  unsigned short* B1t    = (unsigned short*)alloc((size_t)256*640*2);
  unsigned short* BtV    = (unsigned short*)alloc((size_t)128*256*2);
  float*          me     = (float*)alloc(NGRAPH*EMB*4);
  float*          v      = (float*)alloc((size_t)NGRAPH*1280*4);
  unsigned short* xb     = (unsigned short*)alloc((size_t)MP*FEAT*2);
  unsigned short* s1     = (unsigned short*)alloc((size_t)MP*512*2);
  unsigned short* D      = (unsigned short*)alloc((size_t)MP*128*2);
  float*          sc     = (float*)alloc(NNODE*4);

  k_zeroMe     <<<89, 256, 0, stream>>>(cursor, x, msg_w, msg_b, me);
  k_prepScatter<<<10790, 256, 0, stream>>>(ei, et, cursor, spk, node_x, xb,
                                           basis1, root1, B1t, basis2, root2, me, v);
  k_agg1  <<<1378, 256, 0, stream>>>(xb, cursor, spk, comp1, s1, v, BtV);
  k_gemmHD<<<628, 256, 0, stream>>>(s1, xb, B1t, BtV, bias1, D);
  k_score2<<<1250, 256, 0, stream>>>(D, cursor, spk, comp2, batch, sc);
  k_lsm   <<<NGRAPH, 256, 0, stream>>>(sc, out);
}